// Round 2
// baseline (2478.115 us; speedup 1.0000x reference)
//
#include <hip/hip_runtime.h>
#include <hip/hip_bf16.h>

typedef __hip_bfloat16 bf16;

#define N_NODES 100000
#define N_EDGES 1600000
#define HDIM 128
#define LN_EPS 1e-5f

// f32 param arena offsets (elements)
#define OFF_CONV_W      0
#define OFF_CONV_B      81
#define OFF_CONV_SW     84
#define OFF_CONV_SB     165
#define OFF_LIN_W       168
#define OFF_LIN_B       31272
#define OFF_LIN_SW      31400
#define OFF_LIN_SB      62504
#define OFF_SAGE_LW     62632
#define OFF_SAGE_LB     111784
#define OFF_SAGE_RW     112168
#define OFF_LN_G        161320
#define OFF_LN_B        161704
#define OFF_MLP_W1      162088
#define OFF_MLP_B1      178472
#define OFF_MLP_W2      178600
#define OFF_MLP_B2      179240
#define PARAM_TOTAL     179245

__device__ __forceinline__ float b2f(bf16 v) { return __bfloat162float(v); }

struct Ptr17 { const void* p[17]; };

// ---------------- dtype detection ----------------
// flags[0] = 1 if float tensors are float32 (else bf16)
// flags[1] = 1 if edge_index is int64 (else int32)
__global__ void detect_kernel(const unsigned short* __restrict__ xw,
                              const unsigned int* __restrict__ ew,
                              int* __restrict__ flags) {
    __shared__ int sawBigExp, sawHigh;
    if (threadIdx.x == 0) { sawBigExp = 0; sawHigh = 0; }
    __syncthreads();
    int localBig = 0, localHigh = 0;
    for (int i = threadIdx.x; i < 65536; i += 256) {
        unsigned e = (xw[i] >> 7) & 0xFF;          // bf16 exponent field
        if (e >= 0xF0) localBig = 1;               // |v|>=2^113 or NaN: impossible for real bf16 data
    }
    for (int i = threadIdx.x; i < 8192; i += 256) {
        if (ew[2 * i + 1] != 0) localHigh = 1;     // int32 data: odd words are src values (nonzero w.h.p.)
    }
    if (localBig) atomicOr(&sawBigExp, 1);
    if (localHigh) atomicOr(&sawHigh, 1);
    __syncthreads();
    if (threadIdx.x == 0) { flags[0] = sawBigExp; flags[1] = sawHigh ? 0 : 1; }
}

// ---------------- convert all float params to f32 arena ----------------
__global__ void cvt_params_kernel(Ptr17 ptrs, const int* __restrict__ flags,
                                  float* __restrict__ dst) {
    int i = blockIdx.x * 256 + threadIdx.x;
    if (i >= PARAM_TOTAL) return;
    const int ksz[17] = {81,3,81,3,31104,128,31104,128,49152,384,49152,384,384,16384,128,640,5};
    int seg = 0, off = i;
    while (off >= ksz[seg]) { off -= ksz[seg]; ++seg; }
    float v;
    if (flags[0]) v = ((const float*)ptrs.p[seg])[off];
    else          v = b2f(((const bf16*)ptrs.p[seg])[off]);
    dst[i] = v;
}

// ---------------- Stage 1: conv(3x3,VALID)+relu -> linear 243->128, both paths ----------------
__global__ __launch_bounds__(128) void conv_lin_kernel(
    const void* __restrict__ x, const float* __restrict__ P, const int* __restrict__ flags,
    float* __restrict__ xn, float* __restrict__ selfh)
{
    const int NB = 4;
    __shared__ float xs[NB][363];        // 3*11*11
    __shared__ float ys[NB][2][243];     // relu(conv) outputs, path 0 = conv_w, 1 = conv_self_w
    __shared__ float wconv[2][81];
    __shared__ float bconv[2][3];
    int tid = threadIdx.x;
    int n0 = blockIdx.x * NB;

    if (tid < 81) { wconv[0][tid] = P[OFF_CONV_W + tid]; wconv[1][tid] = P[OFF_CONV_SW + tid]; }
    else if (tid < 84) { int o = tid - 81; bconv[0][o] = P[OFF_CONV_B + o]; bconv[1][o] = P[OFF_CONV_SB + o]; }

    if (flags[0]) {
        const float* xf = (const float*)x;
        for (int i = tid; i < NB * 363; i += 128) {
            int j = i / 363, q = i % 363;
            xs[j][q] = xf[(size_t)(n0 + j) * 363 + q];
        }
    } else {
        const bf16* xb = (const bf16*)x;
        for (int i = tid; i < NB * 363; i += 128) {
            int j = i / 363, q = i % 363;
            xs[j][q] = b2f(xb[(size_t)(n0 + j) * 363 + q]);
        }
    }
    __syncthreads();

    for (int u = tid; u < NB * 2 * 243; u += 128) {
        int j = u / 486; int rem = u % 486; int p = rem / 243; int q = rem % 243;
        int o = q / 81; int ij = q % 81; int oi = ij / 9; int oj = ij % 9;
        float acc = bconv[p][o];
        const float* wp = &wconv[p][o * 27];
        const float* xp = &xs[j][oi * 11 + oj];
        #pragma unroll
        for (int c = 0; c < 3; c++)
            #pragma unroll
            for (int ki = 0; ki < 3; ki++)
                #pragma unroll
                for (int kj = 0; kj < 3; kj++)
                    acc += xp[c * 121 + ki * 11 + kj] * wp[c * 9 + ki * 3 + kj];
        ys[j][p][q] = fmaxf(acc, 0.f);
    }
    __syncthreads();

    const float* lin_w  = P + OFF_LIN_W;
    const float* lin_sw = P + OFF_LIN_SW;
    float a0[NB], a1[NB];
    #pragma unroll
    for (int j = 0; j < NB; j++) { a0[j] = 0.f; a1[j] = 0.f; }
    for (int k = 0; k < 243; k++) {
        float w0 = lin_w[k * 128 + tid];
        float w1 = lin_sw[k * 128 + tid];
        #pragma unroll
        for (int j = 0; j < NB; j++) {
            a0[j] += ys[j][0][k] * w0;
            a1[j] += ys[j][1][k] * w1;
        }
    }
    float bb0 = P[OFF_LIN_B + tid], bb1 = P[OFF_LIN_SB + tid];
    #pragma unroll
    for (int j = 0; j < NB; j++) {
        xn[(size_t)(n0 + j) * 128 + tid]    = a0[j] + bb0;
        selfh[(size_t)(n0 + j) * 128 + tid] = a1[j] + bb1;
    }
}

// ---------------- edge loads (dtype-flexible, single load via selected address) ----------------
__device__ __forceinline__ int ld_edge(const int* __restrict__ ew, size_t elem, int isi64) {
    size_t idx = isi64 ? (elem * 2) : elem;   // little-endian low word of int64
    return ew[idx];
}

// ---------------- CSR build ----------------
__global__ void degree_kernel(const int* __restrict__ ew, const int* __restrict__ flags,
                              int* __restrict__ deg) {
    int e = blockIdx.x * blockDim.x + threadIdx.x;
    if (e < N_EDGES) {
        int d = ld_edge(ew, (size_t)N_EDGES + e, flags[1]);
        if ((unsigned)d < N_NODES) atomicAdd(&deg[d], 1);
    }
}

__global__ __launch_bounds__(1024) void scanA(const int* __restrict__ deg, int* __restrict__ rowptr,
                                              float* __restrict__ cntf, int* __restrict__ bsum) {
    __shared__ int s[1024];
    int tid = threadIdx.x;
    int i = blockIdx.x * 1024 + tid;
    int v = (i < N_NODES) ? deg[i] : 0;
    s[tid] = v;
    __syncthreads();
    for (int off = 1; off < 1024; off <<= 1) {
        int t = (tid >= off) ? s[tid - off] : 0;
        __syncthreads();
        s[tid] += t;
        __syncthreads();
    }
    if (i < N_NODES) {
        rowptr[i] = s[tid] - v;                 // local exclusive scan
        cntf[i] = (float)(v < 1 ? 1 : v);
    }
    if (tid == 1023) bsum[blockIdx.x] = s[1023];
}

__global__ void scanB(const int* __restrict__ bsum, int* __restrict__ boff, int nb, int* __restrict__ rowptr_end) {
    if (threadIdx.x == 0 && blockIdx.x == 0) {
        int run = 0;
        for (int i = 0; i < nb; i++) { boff[i] = run; run += bsum[i]; }
        *rowptr_end = run;
    }
}

__global__ __launch_bounds__(1024) void scanC(int* __restrict__ rowptr, const int* __restrict__ boff,
                                              int* __restrict__ cursor) {
    int i = blockIdx.x * 1024 + threadIdx.x;
    if (i < N_NODES) {
        int v = rowptr[i] + boff[blockIdx.x];
        rowptr[i] = v;
        cursor[i] = v;
    }
}

__global__ void fill_kernel(const int* __restrict__ ew, const int* __restrict__ flags,
                            int* __restrict__ cursor, int* __restrict__ csr) {
    int e = blockIdx.x * blockDim.x + threadIdx.x;
    if (e < N_EDGES) {
        int isi64 = flags[1];
        int s = ld_edge(ew, (size_t)e, isi64);
        int d = ld_edge(ew, (size_t)N_EDGES + e, isi64);
        if ((unsigned)d < N_NODES) {
            int p = atomicAdd(&cursor[d], 1);
            if ((unsigned)p < N_EDGES)
                csr[p] = ((unsigned)s < N_NODES) ? (s | ((s == d) ? (int)0x80000000 : 0)) : -1;
        }
    }
}

// ---------------- Aggregations (wave per node, lane = feature) ----------------
__global__ __launch_bounds__(256) void agg0_kernel(const float* __restrict__ xn,
        const int* __restrict__ rowptr, const int* __restrict__ csr,
        float* __restrict__ h /* in: selfh, out: h0 */) {
    int wave = threadIdx.x >> 6, lane = threadIdx.x & 63;
    int n = blockIdx.x * 4 + wave;
    if (n >= N_NODES) return;
    int beg = rowptr[n], end = rowptr[n + 1];
    float a0 = 0.f, a1 = 0.f;
    for (int e = beg; e < end; e++) {
        int sv = csr[e];
        if ((unsigned)sv >= N_NODES) continue;    // self loop (bit31) or invalid
        const float* p = xn + (size_t)sv * 128;
        a0 += p[lane];
        a1 += p[lane + 64];
    }
    size_t base = (size_t)n * 128;
    h[base + lane]      += a0;
    h[base + 64 + lane] += a1;
}

__global__ __launch_bounds__(256) void aggm_kernel(const float* __restrict__ z,
        const int* __restrict__ rowptr, const int* __restrict__ csr,
        const float* __restrict__ cntf, float* __restrict__ agg) {
    int wave = threadIdx.x >> 6, lane = threadIdx.x & 63;
    int n = blockIdx.x * 4 + wave;
    if (n >= N_NODES) return;
    int beg = rowptr[n], end = rowptr[n + 1];
    float a0 = 0.f, a1 = 0.f;
    for (int e = beg; e < end; e++) {
        int sv = csr[e] & 0x7fffffff;             // SAGE keeps self loops
        if (sv >= N_NODES) continue;              // invalid guard
        const float* p = z + (size_t)sv * 128;
        a0 += p[lane];
        a1 += p[lane + 64];
    }
    float inv = 1.f / cntf[n];
    size_t base = (size_t)n * 128;
    agg[base + lane]      = a0 * inv;
    agg[base + 64 + lane] = a1 * inv;
}

// ---------------- relu + LayerNorm (wave per node) ----------------
__global__ __launch_bounds__(256) void lnrelu_kernel(const float* __restrict__ h,
        const float* __restrict__ g, const float* __restrict__ b, float* __restrict__ z) {
    int wave = threadIdx.x >> 6, lane = threadIdx.x & 63;
    int n = blockIdx.x * 4 + wave;
    if (n >= N_NODES) return;
    size_t base = (size_t)n * 128;
    float v0 = fmaxf(h[base + lane], 0.f);
    float v1 = fmaxf(h[base + 64 + lane], 0.f);
    float s = v0 + v1, sq = v0 * v0 + v1 * v1;
    #pragma unroll
    for (int m = 32; m >= 1; m >>= 1) {
        s  += __shfl_xor(s, m, 64);
        sq += __shfl_xor(sq, m, 64);
    }
    float mu = s * (1.f / 128.f);
    float var = sq * (1.f / 128.f) - mu * mu;
    float inv = rsqrtf(var + LN_EPS);
    z[base + lane]      = (v0 - mu) * inv * g[lane]      + b[lane];
    z[base + 64 + lane] = (v1 - mu) * inv * g[lane + 64] + b[lane + 64];
}

// ---------------- SAGE linear: hnew = agg@lw + lb + z@rw ----------------
__global__ __launch_bounds__(128) void sage_kernel(const float* __restrict__ agg, const float* __restrict__ z,
        const float* __restrict__ lw, const float* __restrict__ lb, const float* __restrict__ rw,
        float* __restrict__ hnew) {
    const int NB = 8;
    __shared__ float ag[NB][128];
    __shared__ float zr[NB][128];
    int tid = threadIdx.x;
    int n0 = blockIdx.x * NB;
    for (int i = tid; i < NB * 128; i += 128) {
        int j = i >> 7, k = i & 127;
        ag[j][k] = agg[(size_t)(n0 + j) * 128 + k];
        zr[j][k] = z[(size_t)(n0 + j) * 128 + k];
    }
    __syncthreads();
    float acc[NB];
    float bb = lb[tid];
    #pragma unroll
    for (int j = 0; j < NB; j++) acc[j] = bb;
    for (int k = 0; k < 128; k++) {
        float wl = lw[k * 128 + tid];
        float wr = rw[k * 128 + tid];
        #pragma unroll
        for (int j = 0; j < NB; j++) acc[j] += ag[j][k] * wl + zr[j][k] * wr;
    }
    #pragma unroll
    for (int j = 0; j < NB; j++) hnew[(size_t)(n0 + j) * 128 + tid] = acc[j];
}

// ---------------- cast emb to output dtype ----------------
__global__ void cast_kernel(const float* __restrict__ h, void* __restrict__ out,
                            const int* __restrict__ flags, int n) {
    int i = blockIdx.x * 256 + threadIdx.x;
    if (i < n) {
        float v = h[i];
        if (flags[0]) ((float*)out)[i] = v;
        else          ((bf16*)out)[i] = __float2bfloat16(v);
    }
}

// ---------------- MLP head + log_softmax ----------------
__global__ __launch_bounds__(128) void mlp_kernel(const float* __restrict__ h,
        const float* __restrict__ P, const int* __restrict__ flags,
        void* __restrict__ out /* base of d_out */) {
    const int NB = 8;
    __shared__ float r[NB][128];
    __shared__ float m[NB][128];
    __shared__ float lg[NB][5];
    int tid = threadIdx.x;
    int n0 = blockIdx.x * NB;
    for (int i = tid; i < NB * 128; i += 128) {
        int j = i >> 7, k = i & 127;
        r[j][k] = fmaxf(h[(size_t)(n0 + j) * 128 + k], 0.f);
    }
    __syncthreads();
    const float* w1 = P + OFF_MLP_W1;
    float acc[NB];
    float bb = P[OFF_MLP_B1 + tid];
    #pragma unroll
    for (int j = 0; j < NB; j++) acc[j] = bb;
    for (int k = 0; k < 128; k++) {
        float w = w1[k * 128 + tid];
        #pragma unroll
        for (int j = 0; j < NB; j++) acc[j] += r[j][k] * w;
    }
    #pragma unroll
    for (int j = 0; j < NB; j++) m[j][tid] = acc[j];
    __syncthreads();
    if (tid < NB * 5) {
        int j = tid / 5, o = tid % 5;
        float a = P[OFF_MLP_B2 + o];
        const float* w2 = P + OFF_MLP_W2;
        for (int k = 0; k < 128; k++) a += m[j][k] * w2[k * 5 + o];
        lg[j][o] = a;
    }
    __syncthreads();
    if (tid < NB) {
        int j = tid;
        float mx = lg[j][0];
        #pragma unroll
        for (int o = 1; o < 5; o++) mx = fmaxf(mx, lg[j][o]);
        float se = 0.f;
        #pragma unroll
        for (int o = 0; o < 5; o++) se += expf(lg[j][o] - mx);
        float lse = mx + logf(se);
        size_t base = (size_t)N_NODES * 128 + (size_t)(n0 + j) * 5;
        int isf = flags[0];
        #pragma unroll
        for (int o = 0; o < 5; o++) {
            float v = lg[j][o] - lse;
            if (isf) ((float*)out)[base + o] = v;
            else     ((bf16*)out)[base + o] = __float2bfloat16(v);
        }
    }
}

extern "C" void kernel_launch(void* const* d_in, const int* in_sizes, int n_in,
                              void* d_out, int out_size, void* d_ws, size_t ws_size,
                              hipStream_t stream) {
    const void* x  = d_in[0];
    const int*  ew = (const int*)d_in[1];   // 32-bit word view of edge_index

    Ptr17 ptrs;
    for (int i = 0; i < 17; i++) ptrs.p[i] = d_in[2 + i];

    char* w = (char*)d_ws;
    float* bufA = (float*)w; w += (size_t)N_NODES * 128 * 4;   // xn, later agg
    float* bufB = (float*)w; w += (size_t)N_NODES * 128 * 4;   // selfh -> h
    float* bufC = (float*)w; w += (size_t)N_NODES * 128 * 4;   // z
    float* pf32 = (float*)w; w += (size_t)((PARAM_TOTAL + 63) & ~63) * 4;
    int*   deg    = (int*)w;   w += (size_t)N_NODES * 4;
    int*   rowptr = (int*)w;   w += (size_t)(N_NODES + 64) * 4;
    int*   cursor = (int*)w;   w += (size_t)N_NODES * 4;
    float* cntf   = (float*)w; w += (size_t)N_NODES * 4;
    int*   bsum   = (int*)w;   w += 128 * 4;
    int*   boff   = (int*)w;   w += 128 * 4;
    int*   flags  = (int*)w;   w += 64 * 4;
    int*   csr    = (int*)w;   w += (size_t)N_EDGES * 4;

    const int SCAN_BLOCKS = (N_NODES + 1023) / 1024;

    detect_kernel<<<1, 256, 0, stream>>>((const unsigned short*)x, (const unsigned int*)ew, flags);
    cvt_params_kernel<<<(PARAM_TOTAL + 255) / 256, 256, 0, stream>>>(ptrs, flags, pf32);

    hipMemsetAsync(deg, 0, (size_t)N_NODES * 4, stream);

    conv_lin_kernel<<<N_NODES / 4, 128, 0, stream>>>(x, pf32, flags, bufA, bufB);

    degree_kernel<<<(N_EDGES + 255) / 256, 256, 0, stream>>>(ew, flags, deg);
    scanA<<<SCAN_BLOCKS, 1024, 0, stream>>>(deg, rowptr, cntf, bsum);
    scanB<<<1, 1, 0, stream>>>(bsum, boff, SCAN_BLOCKS, rowptr + N_NODES);
    scanC<<<SCAN_BLOCKS, 1024, 0, stream>>>(rowptr, boff, cursor);
    fill_kernel<<<(N_EDGES + 255) / 256, 256, 0, stream>>>(ew, flags, cursor, csr);

    agg0_kernel<<<N_NODES / 4, 256, 0, stream>>>(bufA, rowptr, csr, bufB);   // h0 in bufB

    for (int l = 0; l < 3; l++) {
        lnrelu_kernel<<<N_NODES / 4, 256, 0, stream>>>(bufB, pf32 + OFF_LN_G + l * 128,
                                                       pf32 + OFF_LN_B + l * 128, bufC);
        aggm_kernel<<<N_NODES / 4, 256, 0, stream>>>(bufC, rowptr, csr, cntf, bufA);
        sage_kernel<<<N_NODES / 8, 128, 0, stream>>>(bufA, bufC, pf32 + OFF_SAGE_LW + l * 16384,
                                                     pf32 + OFF_SAGE_LB + l * 128,
                                                     pf32 + OFF_SAGE_RW + l * 16384, bufB);
    }

    cast_kernel<<<(N_NODES * 128 + 255) / 256, 256, 0, stream>>>(bufB, d_out, flags, N_NODES * 128);
    mlp_kernel<<<N_NODES / 8, 128, 0, stream>>>(bufB, pf32, flags, d_out);
}

// Round 3
// 1543.920 us; speedup vs baseline: 1.6051x; 1.6051x over previous
//
#include <hip/hip_runtime.h>
#include <hip/hip_bf16.h>

typedef __hip_bfloat16 bf16;
typedef __attribute__((ext_vector_type(8))) short v8s;
typedef __attribute__((ext_vector_type(4))) float v4f;

#define N_NODES 100000
#define N_EDGES 1600000
#define LN_EPS 1e-5f

// f32 param arena offsets (elements)
#define OFF_CONV_W      0
#define OFF_CONV_B      81
#define OFF_CONV_SW     84
#define OFF_CONV_SB     165
#define OFF_LIN_W       168
#define OFF_LIN_B       31272
#define OFF_LIN_SW      31400
#define OFF_LIN_SB      62504
#define OFF_SAGE_LW     62632
#define OFF_SAGE_LB     111784
#define OFF_SAGE_RW     112168
#define OFF_LN_G        161320
#define OFF_LN_B        161704
#define OFF_MLP_W1      162088
#define OFF_MLP_B1      178472
#define OFF_MLP_W2      178600
#define OFF_MLP_B2      179240
#define PARAM_TOTAL     179245

#define WTL_N 65536     // [256 f][256 k]  conv-linear (f<128: lin_w, f>=128: lin_self_w)
#define WTS_N 98304     // 3 x [128 f][256 k]  sage (k<128: lw, k>=128: rw)
#define WTM_N 16384     // [128 f][128 k]  mlp_w1

__device__ __forceinline__ unsigned short f2b(float f) {
    bf16 h = __float2bfloat16(f);
    return __builtin_bit_cast(unsigned short, h);
}
__device__ __forceinline__ float blo(unsigned u) { return __uint_as_float(u << 16); }
__device__ __forceinline__ float bhi(unsigned u) { return __uint_as_float(u & 0xffff0000u); }

struct Ptr17 { const void* p[17]; };

// ---------------- dtype detection ----------------
__global__ void detect_kernel(const unsigned short* __restrict__ xw,
                              const unsigned int* __restrict__ ew,
                              int* __restrict__ flags) {
    __shared__ int sawBigExp, sawHigh;
    if (threadIdx.x == 0) { sawBigExp = 0; sawHigh = 0; }
    __syncthreads();
    int localBig = 0, localHigh = 0;
    for (int i = threadIdx.x; i < 65536; i += 256) {
        unsigned e = (xw[i] >> 7) & 0xFF;
        if (e >= 0xF0) localBig = 1;
    }
    for (int i = threadIdx.x; i < 8192; i += 256) {
        if (ew[2 * i + 1] != 0) localHigh = 1;
    }
    if (localBig) atomicOr(&sawBigExp, 1);
    if (localHigh) atomicOr(&sawHigh, 1);
    __syncthreads();
    if (threadIdx.x == 0) { flags[0] = sawBigExp; flags[1] = sawHigh ? 0 : 1; }
}

// ---------------- convert all float params to f32 arena ----------------
__global__ void cvt_params_kernel(Ptr17 ptrs, const int* __restrict__ flags,
                                  float* __restrict__ dst) {
    int i = blockIdx.x * 256 + threadIdx.x;
    if (i >= PARAM_TOTAL) return;
    const int ksz[17] = {81,3,81,3,31104,128,31104,128,49152,384,49152,384,384,16384,128,640,5};
    int seg = 0, off = i;
    while (off >= ksz[seg]) { off -= ksz[seg]; ++seg; }
    float v;
    if (flags[0]) v = ((const float*)ptrs.p[seg])[off];
    else          v = __bfloat162float(((const bf16*)ptrs.p[seg])[off]);
    dst[i] = v;
}

// ---------------- build bf16 transposed weight arenas ----------------
__global__ void cvt2_kernel(const float* __restrict__ P,
                            unsigned short* __restrict__ wtl,
                            unsigned short* __restrict__ wts,
                            unsigned short* __restrict__ wtm) {
    int i = blockIdx.x * 256 + threadIdx.x;
    if (i < WTL_N) {
        int f = i >> 8, k = i & 255;
        float v = 0.f;
        if (k < 243) v = (f < 128) ? P[OFF_LIN_W + k * 128 + f]
                                   : P[OFF_LIN_SW + k * 128 + (f - 128)];
        wtl[i] = f2b(v);
    } else if (i < WTL_N + WTS_N) {
        int j = i - WTL_N; int l = j >> 15; int r = j & 32767; int f = r >> 8; int k = r & 255;
        float v = (k < 128) ? P[OFF_SAGE_LW + l * 16384 + k * 128 + f]
                            : P[OFF_SAGE_RW + l * 16384 + (k - 128) * 128 + f];
        wts[j] = f2b(v);
    } else if (i < WTL_N + WTS_N + WTM_N) {
        int j = i - WTL_N - WTS_N; int f = j >> 7, k = j & 127;
        wtm[j] = f2b(P[OFF_MLP_W1 + k * 128 + f]);
    }
}

// ---------------- Stage 1: conv+relu (VALU) -> 243->256 linear (MFMA) ----------------
__global__ __launch_bounds__(256) void conv_lin_kernel(
    const void* __restrict__ x, const float* __restrict__ P,
    const unsigned short* __restrict__ wtl, const int* __restrict__ flags,
    unsigned short* __restrict__ xnb, float* __restrict__ selfh)
{
    __shared__ float xs[16][363];                 // 16 nodes x 3*11*11
    __shared__ unsigned short ysb[16][2][256];    // relu(conv) bf16, K padded to 256
    __shared__ float wconv[2][81];
    __shared__ float bconv[2][3];
    int tid = threadIdx.x;
    int n0 = blockIdx.x * 16;

    if (tid < 81) { wconv[0][tid] = P[OFF_CONV_W + tid]; wconv[1][tid] = P[OFF_CONV_SW + tid]; }
    else if (tid < 84) { int o = tid - 81; bconv[0][o] = P[OFF_CONV_B + o]; bconv[1][o] = P[OFF_CONV_SB + o]; }

    {   // zero ysb (covers K padding 243..255)
        unsigned int* z = (unsigned int*)ysb;
        #pragma unroll
        for (int i = tid; i < 16 * 2 * 128; i += 256) z[i] = 0;
    }
    if (flags[0]) {
        const float* xf = (const float*)x;
        for (int i = tid; i < 16 * 363; i += 256) {
            int j = i / 363, q = i - j * 363;
            xs[j][q] = xf[(size_t)(n0 + j) * 363 + q];
        }
    } else {
        const unsigned short* xb = (const unsigned short*)x;
        for (int i = tid; i < 16 * 363; i += 256) {
            int j = i / 363, q = i - j * 363;
            xs[j][q] = blo(xb[(size_t)(n0 + j) * 363 + q]);
        }
    }
    __syncthreads();

    // conv: work item = (node j, path p, output row oi) -> 27 outputs (3 o x 9 oj)
    for (int u = tid; u < 288; u += 256) {
        int j = u / 18, rem = u - j * 18;
        int p = rem / 9, oi = rem - p * 9;
        float acc[27];
        #pragma unroll
        for (int o = 0; o < 3; o++) {
            float b = bconv[p][o];
            #pragma unroll
            for (int oj = 0; oj < 9; oj++) acc[o * 9 + oj] = b;
        }
        #pragma unroll
        for (int c = 0; c < 3; c++) {
            #pragma unroll
            for (int ki = 0; ki < 3; ki++) {
                float xr[11];
                const float* row = &xs[j][c * 121 + (oi + ki) * 11];
                #pragma unroll
                for (int t = 0; t < 11; t++) xr[t] = row[t];
                #pragma unroll
                for (int o = 0; o < 3; o++) {
                    int wb = o * 27 + c * 9 + ki * 3;
                    float w0 = wconv[p][wb], w1 = wconv[p][wb + 1], w2 = wconv[p][wb + 2];
                    #pragma unroll
                    for (int oj = 0; oj < 9; oj++)
                        acc[o * 9 + oj] += xr[oj] * w0 + xr[oj + 1] * w1 + xr[oj + 2] * w2;
                }
            }
        }
        #pragma unroll
        for (int o = 0; o < 3; o++)
            #pragma unroll
            for (int oj = 0; oj < 9; oj++)
                ysb[j][p][o * 81 + oi * 9 + oj] = f2b(fmaxf(acc[o * 9 + oj], 0.f));
    }
    __syncthreads();

    // MFMA: [16 nodes][256 k] x [256 k][256 f]; waves 0-1 -> path0 (f 0..127), 2-3 -> path1
    int wave = tid >> 6, lane = tid & 63, quad = lane >> 4, col = lane & 15;
    int p = wave >> 1;
    v4f acc[4];
    #pragma unroll
    for (int t = 0; t < 4; t++) { acc[t][0] = 0.f; acc[t][1] = 0.f; acc[t][2] = 0.f; acc[t][3] = 0.f; }
    for (int s = 0; s < 8; s++) {
        int kq = s * 32 + quad * 8;
        v8s a = *(const v8s*)&ysb[col][p][kq];
        #pragma unroll
        for (int t = 0; t < 4; t++) {
            int f = (wave * 4 + t) * 16 + col;
            v8s b = *(const v8s*)&wtl[(size_t)f * 256 + kq];
            acc[t] = __builtin_amdgcn_mfma_f32_16x16x32_bf16(a, b, acc[t], 0, 0, 0);
        }
    }
    #pragma unroll
    for (int t = 0; t < 4; t++) {
        int f = (wave * 4 + t) * 16 + col;
        #pragma unroll
        for (int r = 0; r < 4; r++) {
            int node = n0 + quad * 4 + r;
            float v = acc[t][r];
            if (p == 0) xnb[(size_t)node * 128 + f] = f2b(v + P[OFF_LIN_B + f]);
            else        selfh[(size_t)node * 128 + (f - 128)] = v + P[OFF_LIN_SB + (f - 128)];
        }
    }
}

// ---------------- edge loads ----------------
__device__ __forceinline__ int ld_edge(const int* __restrict__ ew, size_t elem, int isi64) {
    size_t idx = isi64 ? (elem * 2) : elem;
    return ew[idx];
}

// ---------------- CSR build ----------------
__global__ void degree_kernel(const int* __restrict__ ew, const int* __restrict__ flags,
                              int* __restrict__ deg) {
    int e = blockIdx.x * blockDim.x + threadIdx.x;
    if (e < N_EDGES) {
        int d = ld_edge(ew, (size_t)N_EDGES + e, flags[1]);
        if ((unsigned)d < N_NODES) atomicAdd(&deg[d], 1);
    }
}

__global__ __launch_bounds__(1024) void scanA(const int* __restrict__ deg, int* __restrict__ rowptr,
                                              float* __restrict__ cntf, int* __restrict__ bsum) {
    __shared__ int s[1024];
    int tid = threadIdx.x;
    int i = blockIdx.x * 1024 + tid;
    int v = (i < N_NODES) ? deg[i] : 0;
    s[tid] = v;
    __syncthreads();
    for (int off = 1; off < 1024; off <<= 1) {
        int t = (tid >= off) ? s[tid - off] : 0;
        __syncthreads();
        s[tid] += t;
        __syncthreads();
    }
    if (i < N_NODES) {
        rowptr[i] = s[tid] - v;
        cntf[i] = (float)(v < 1 ? 1 : v);
    }
    if (tid == 1023) bsum[blockIdx.x] = s[1023];
}

__global__ void scanB(const int* __restrict__ bsum, int* __restrict__ boff, int nb, int* __restrict__ rowptr_end) {
    if (threadIdx.x == 0 && blockIdx.x == 0) {
        int run = 0;
        for (int i = 0; i < nb; i++) { boff[i] = run; run += bsum[i]; }
        *rowptr_end = run;
    }
}

__global__ __launch_bounds__(1024) void scanC(int* __restrict__ rowptr, const int* __restrict__ boff,
                                              int* __restrict__ cursor) {
    int i = blockIdx.x * 1024 + threadIdx.x;
    if (i < N_NODES) {
        int v = rowptr[i] + boff[blockIdx.x];
        rowptr[i] = v;
        cursor[i] = v;
    }
}

__global__ void fill_kernel(const int* __restrict__ ew, const int* __restrict__ flags,
                            int* __restrict__ cursor, int* __restrict__ csr) {
    int e = blockIdx.x * blockDim.x + threadIdx.x;
    if (e < N_EDGES) {
        int isi64 = flags[1];
        int s = ld_edge(ew, (size_t)e, isi64);
        int d = ld_edge(ew, (size_t)N_EDGES + e, isi64);
        if ((unsigned)d < N_NODES) {
            int p = atomicAdd(&cursor[d], 1);
            if ((unsigned)p < N_EDGES)
                csr[p] = ((unsigned)s < N_NODES) ? (s | ((s == d) ? (int)0x80000000 : 0)) : -1;
        }
    }
}

// ---------------- agg0 + relu + LN0 (wave per node, paired features 2*lane, 2*lane+1) ----------------
__global__ __launch_bounds__(256) void agg0ln_kernel(const unsigned short* __restrict__ xnb,
        const float* __restrict__ selfh, const int* __restrict__ rowptr, const int* __restrict__ csr,
        const float* __restrict__ lng, const float* __restrict__ lnb,
        unsigned short* __restrict__ zb) {
    int wave = threadIdx.x >> 6, lane = threadIdx.x & 63;
    int n = blockIdx.x * 4 + wave;
    int beg = rowptr[n], end = rowptr[n + 1];
    float a0 = 0.f, a1 = 0.f;
    const unsigned int* xb32 = (const unsigned int*)xnb;
    for (int e = beg; e < end; e++) {
        int sv = csr[e];
        if ((unsigned)sv >= N_NODES) continue;      // self loop (bit31) or invalid
        unsigned u = xb32[(size_t)sv * 64 + lane];
        a0 += blo(u);
        a1 += bhi(u);
    }
    const float2* s2 = (const float2*)selfh;
    float2 sv2 = s2[(size_t)n * 64 + lane];
    float v0 = fmaxf(sv2.x + a0, 0.f);
    float v1 = fmaxf(sv2.y + a1, 0.f);
    float s = v0 + v1, sq = v0 * v0 + v1 * v1;
    #pragma unroll
    for (int m = 32; m >= 1; m >>= 1) {
        s  += __shfl_xor(s, m, 64);
        sq += __shfl_xor(sq, m, 64);
    }
    float mu = s * (1.f / 128.f);
    float var = sq * (1.f / 128.f) - mu * mu;
    float inv = rsqrtf(var + LN_EPS);
    float z0 = (v0 - mu) * inv * lng[2 * lane]     + lnb[2 * lane];
    float z1 = (v1 - mu) * inv * lng[2 * lane + 1] + lnb[2 * lane + 1];
    ((unsigned int*)zb)[(size_t)n * 64 + lane] = (unsigned)f2b(z0) | ((unsigned)f2b(z1) << 16);
}

// ---------------- SAGE mean aggregation (bf16 gather -> bf16 agg) ----------------
__global__ __launch_bounds__(256) void aggm_kernel(const unsigned short* __restrict__ zb,
        const int* __restrict__ rowptr, const int* __restrict__ csr,
        const float* __restrict__ cntf, unsigned short* __restrict__ aggb) {
    int wave = threadIdx.x >> 6, lane = threadIdx.x & 63;
    int n = blockIdx.x * 4 + wave;
    int beg = rowptr[n], end = rowptr[n + 1];
    float a0 = 0.f, a1 = 0.f;
    const unsigned int* zb32 = (const unsigned int*)zb;
    int e = beg;
    for (; e + 1 < end; e += 2) {                    // 2-deep for MLP
        int s0 = csr[e] & 0x7fffffff;
        int s1 = csr[e + 1] & 0x7fffffff;
        unsigned u0 = (s0 < N_NODES) ? zb32[(size_t)s0 * 64 + lane] : 0u;
        unsigned u1 = (s1 < N_NODES) ? zb32[(size_t)s1 * 64 + lane] : 0u;
        a0 += blo(u0) + blo(u1);
        a1 += bhi(u0) + bhi(u1);
    }
    for (; e < end; e++) {
        int sv = csr[e] & 0x7fffffff;
        if (sv >= N_NODES) continue;
        unsigned u = zb32[(size_t)sv * 64 + lane];
        a0 += blo(u);
        a1 += bhi(u);
    }
    float inv = 1.f / cntf[n];
    ((unsigned int*)aggb)[(size_t)n * 64 + lane] =
        (unsigned)f2b(a0 * inv) | ((unsigned)f2b(a1 * inv) << 16);
}

// ---------------- SAGE update (MFMA, concat-K) + fused relu+LN (or final h) ----------------
__global__ __launch_bounds__(256) void sageln_kernel(const unsigned short* __restrict__ aggb,
        unsigned short* __restrict__ zb, const unsigned short* __restrict__ wts,
        const float* __restrict__ lb, const float* __restrict__ lng, const float* __restrict__ lnb,
        int last, float* __restrict__ hout) {
    __shared__ float hb[16][128];
    int tid = threadIdx.x;
    int n0 = blockIdx.x * 16;
    int wave = tid >> 6, lane = tid & 63, quad = lane >> 4, col = lane & 15;
    int nodeA = n0 + col;

    v4f acc[2];
    #pragma unroll
    for (int t = 0; t < 2; t++) { acc[t][0] = 0.f; acc[t][1] = 0.f; acc[t][2] = 0.f; acc[t][3] = 0.f; }
    #pragma unroll
    for (int s = 0; s < 8; s++) {
        int kq = s * 32 + quad * 8;
        const unsigned short* abase = (s < 4) ? (aggb + (size_t)nodeA * 128 + kq)
                                              : (zb + (size_t)nodeA * 128 + (kq - 128));
        v8s a = *(const v8s*)abase;
        #pragma unroll
        for (int t = 0; t < 2; t++) {
            int f = (wave * 2 + t) * 16 + col;
            v8s b = *(const v8s*)&wts[(size_t)f * 256 + kq];
            acc[t] = __builtin_amdgcn_mfma_f32_16x16x32_bf16(a, b, acc[t], 0, 0, 0);
        }
    }
    #pragma unroll
    for (int t = 0; t < 2; t++) {
        int f = (wave * 2 + t) * 16 + col;
        float bias = lb[f];
        #pragma unroll
        for (int r = 0; r < 4; r++)
            hb[quad * 4 + r][f] = acc[t][r] + bias;
    }
    __syncthreads();

    #pragma unroll
    for (int jj = 0; jj < 4; jj++) {
        int j = wave * 4 + jj;
        int node = n0 + j;
        float v0 = hb[j][2 * lane], v1 = hb[j][2 * lane + 1];
        if (last) {
            float2 w; w.x = v0; w.y = v1;
            ((float2*)hout)[(size_t)node * 64 + lane] = w;
        } else {
            float r0 = fmaxf(v0, 0.f), r1 = fmaxf(v1, 0.f);
            float s = r0 + r1, sq = r0 * r0 + r1 * r1;
            #pragma unroll
            for (int m = 32; m >= 1; m >>= 1) {
                s  += __shfl_xor(s, m, 64);
                sq += __shfl_xor(sq, m, 64);
            }
            float mu = s * (1.f / 128.f);
            float var = sq * (1.f / 128.f) - mu * mu;
            float inv = rsqrtf(var + LN_EPS);
            float z0 = (r0 - mu) * inv * lng[2 * lane]     + lnb[2 * lane];
            float z1 = (r1 - mu) * inv * lng[2 * lane + 1] + lnb[2 * lane + 1];
            ((unsigned int*)zb)[(size_t)node * 64 + lane] =
                (unsigned)f2b(z0) | ((unsigned)f2b(z1) << 16);
        }
    }
}

// ---------------- MLP head (MFMA w1) + log_softmax + fused emb cast ----------------
__global__ __launch_bounds__(256) void mlp_kernel(const float* __restrict__ h,
        const unsigned short* __restrict__ wtm, const float* __restrict__ P,
        const int* __restrict__ flags, void* __restrict__ out) {
    __shared__ unsigned short rb[16][128];
    __shared__ float mb[16][128];
    __shared__ float lg[16][5];
    int tid = threadIdx.x;
    int n0 = blockIdx.x * 16;
    int isf = flags[0];

    const float2* h2 = (const float2*)h;
    for (int i = tid; i < 16 * 64; i += 256) {
        int j = i >> 6, q = i & 63;
        float2 v = h2[(size_t)(n0 + j) * 64 + q];
        size_t oi = (size_t)(n0 + j) * 128 + 2 * q;
        if (isf) { ((float*)out)[oi] = v.x; ((float*)out)[oi + 1] = v.y; }
        else ((unsigned int*)out)[oi >> 1] = (unsigned)f2b(v.x) | ((unsigned)f2b(v.y) << 16);
        rb[j][2 * q]     = f2b(fmaxf(v.x, 0.f));
        rb[j][2 * q + 1] = f2b(fmaxf(v.y, 0.f));
    }
    __syncthreads();

    int wave = tid >> 6, lane = tid & 63, quad = lane >> 4, col = lane & 15;
    v4f acc[2];
    #pragma unroll
    for (int t = 0; t < 2; t++) { acc[t][0] = 0.f; acc[t][1] = 0.f; acc[t][2] = 0.f; acc[t][3] = 0.f; }
    #pragma unroll
    for (int s = 0; s < 4; s++) {
        int kq = s * 32 + quad * 8;
        v8s a = *(const v8s*)&rb[col][kq];
        #pragma unroll
        for (int t = 0; t < 2; t++) {
            int f = (wave * 2 + t) * 16 + col;
            v8s b = *(const v8s*)&wtm[(size_t)f * 128 + kq];
            acc[t] = __builtin_amdgcn_mfma_f32_16x16x32_bf16(a, b, acc[t], 0, 0, 0);
        }
    }
    #pragma unroll
    for (int t = 0; t < 2; t++) {
        int f = (wave * 2 + t) * 16 + col;
        float bias = P[OFF_MLP_B1 + f];
        #pragma unroll
        for (int r = 0; r < 4; r++)
            mb[quad * 4 + r][f] = acc[t][r] + bias;
    }
    __syncthreads();

    if (tid < 80) {
        int j = tid / 5, o = tid - (tid / 5) * 5;
        float a = P[OFF_MLP_B2 + o];
        for (int k = 0; k < 128; k++) a += mb[j][k] * P[OFF_MLP_W2 + k * 5 + o];
        lg[j][o] = a;
    }
    __syncthreads();
    if (tid < 16) {
        int j = tid;
        float mx = lg[j][0];
        #pragma unroll
        for (int o = 1; o < 5; o++) mx = fmaxf(mx, lg[j][o]);
        float se = 0.f;
        #pragma unroll
        for (int o = 0; o < 5; o++) se += expf(lg[j][o] - mx);
        float lse = mx + logf(se);
        size_t base = (size_t)N_NODES * 128 + (size_t)(n0 + j) * 5;
        #pragma unroll
        for (int o = 0; o < 5; o++) {
            float v = lg[j][o] - lse;
            if (isf) ((float*)out)[base + o] = v;
            else     ((bf16*)out)[base + o] = __float2bfloat16(v);
        }
    }
}

extern "C" void kernel_launch(void* const* d_in, const int* in_sizes, int n_in,
                              void* d_out, int out_size, void* d_ws, size_t ws_size,
                              hipStream_t stream) {
    const void* x  = d_in[0];
    const int*  ew = (const int*)d_in[1];

    Ptr17 ptrs;
    for (int i = 0; i < 17; i++) ptrs.p[i] = d_in[2 + i];

    char* w = (char*)d_ws;
    auto carve = [&](size_t bytes) { char* r = w; w += (bytes + 255) & ~(size_t)255; return r; };
    float*          bufS  = (float*)carve((size_t)N_NODES * 128 * 4);   // selfh, later final h
    unsigned short* xnb   = (unsigned short*)carve((size_t)N_NODES * 128 * 2);
    unsigned short* zb    = (unsigned short*)carve((size_t)N_NODES * 128 * 2);
    unsigned short* aggb  = (unsigned short*)carve((size_t)N_NODES * 128 * 2);
    float*          pf32  = (float*)carve((size_t)PARAM_TOTAL * 4);
    unsigned short* wtl   = (unsigned short*)carve((size_t)WTL_N * 2);
    unsigned short* wts   = (unsigned short*)carve((size_t)WTS_N * 2);
    unsigned short* wtm   = (unsigned short*)carve((size_t)WTM_N * 2);
    int*   deg    = (int*)carve((size_t)N_NODES * 4);
    int*   rowptr = (int*)carve((size_t)(N_NODES + 64) * 4);
    int*   cursor = (int*)carve((size_t)N_NODES * 4);
    float* cntf   = (float*)carve((size_t)N_NODES * 4);
    int*   bsum   = (int*)carve(512);
    int*   boff   = (int*)carve(512);
    int*   flags  = (int*)carve(256);
    int*   csr    = (int*)carve((size_t)N_EDGES * 4);

    const int SCAN_BLOCKS = (N_NODES + 1023) / 1024;

    detect_kernel<<<1, 256, 0, stream>>>((const unsigned short*)x, (const unsigned int*)ew, flags);
    cvt_params_kernel<<<(PARAM_TOTAL + 255) / 256, 256, 0, stream>>>(ptrs, flags, pf32);
    cvt2_kernel<<<(WTL_N + WTS_N + WTM_N + 255) / 256, 256, 0, stream>>>(pf32, wtl, wts, wtm);

    hipMemsetAsync(deg, 0, (size_t)N_NODES * 4, stream);

    conv_lin_kernel<<<N_NODES / 16, 256, 0, stream>>>(x, pf32, wtl, flags, xnb, bufS);

    degree_kernel<<<(N_EDGES + 255) / 256, 256, 0, stream>>>(ew, flags, deg);
    scanA<<<SCAN_BLOCKS, 1024, 0, stream>>>(deg, rowptr, cntf, bsum);
    scanB<<<1, 1, 0, stream>>>(bsum, boff, SCAN_BLOCKS, rowptr + N_NODES);
    scanC<<<SCAN_BLOCKS, 1024, 0, stream>>>(rowptr, boff, cursor);
    fill_kernel<<<(N_EDGES + 255) / 256, 256, 0, stream>>>(ew, flags, cursor, csr);

    agg0ln_kernel<<<N_NODES / 4, 256, 0, stream>>>(xnb, bufS, rowptr, csr,
        pf32 + OFF_LN_G, pf32 + OFF_LN_B, zb);

    for (int l = 0; l < 3; l++) {
        aggm_kernel<<<N_NODES / 4, 256, 0, stream>>>(zb, rowptr, csr, cntf, aggb);
        sageln_kernel<<<N_NODES / 16, 256, 0, stream>>>(aggb, zb, wts + (size_t)l * 32768,
            pf32 + OFF_SAGE_LB + l * 128,
            pf32 + OFF_LN_G + (l + 1) * 128, pf32 + OFF_LN_B + (l + 1) * 128,
            (l == 2) ? 1 : 0, bufS);
    }

    mlp_kernel<<<N_NODES / 16, 256, 0, stream>>>(bufS, wtm, pf32, flags, d_out);
}

// Round 4
// 1263.509 us; speedup vs baseline: 1.9613x; 1.2219x over previous
//
#include <hip/hip_runtime.h>
#include <hip/hip_bf16.h>

typedef __hip_bfloat16 bf16;
typedef __attribute__((ext_vector_type(8))) short v8s;
typedef __attribute__((ext_vector_type(4))) float v4f;

#define N_NODES 100000
#define N_EDGES 1600000
#define LN_EPS 1e-5f

// f32 param arena offsets (elements)
#define OFF_CONV_W      0
#define OFF_CONV_B      81
#define OFF_CONV_SW     84
#define OFF_CONV_SB     165
#define OFF_LIN_W       168
#define OFF_LIN_B       31272
#define OFF_LIN_SW      31400
#define OFF_LIN_SB      62504
#define OFF_SAGE_LW     62632
#define OFF_SAGE_LB     111784
#define OFF_SAGE_RW     112168
#define OFF_LN_G        161320
#define OFF_LN_B        161704
#define OFF_MLP_W1      162088
#define OFF_MLP_B1      178472
#define OFF_MLP_W2      178600
#define OFF_MLP_B2      179240
#define PARAM_TOTAL     179245

#define WTL_N 65536     // [256 f][256 k]  conv-linear (f<128: lin_w, f>=128: lin_self_w)
#define WTS_N 98304     // 3 x [128 f][256 k]  sage (k<128: lw, k>=128: rw)
#define WTM_N 16384     // [128 f][128 k]  mlp_w1

#define CONV_NB 14      // nodes per conv block: 14*18 = 252 units <= 256 threads (1 unit/thread)

__device__ __forceinline__ unsigned short f2b(float f) {
    bf16 h = __float2bfloat16(f);
    return __builtin_bit_cast(unsigned short, h);
}
__device__ __forceinline__ float blo(unsigned u) { return __uint_as_float(u << 16); }
__device__ __forceinline__ float bhi(unsigned u) { return __uint_as_float(u & 0xffff0000u); }
__device__ __forceinline__ unsigned pack2(float lo, float hi) {
    return (unsigned)f2b(lo) | ((unsigned)f2b(hi) << 16);
}

struct Ptr17 { const void* p[17]; };

// ---------------- dtype detection ----------------
__global__ void detect_kernel(const unsigned short* __restrict__ xw,
                              const unsigned int* __restrict__ ew,
                              int* __restrict__ flags) {
    __shared__ int sawBigExp, sawHigh;
    if (threadIdx.x == 0) { sawBigExp = 0; sawHigh = 0; }
    __syncthreads();
    int localBig = 0, localHigh = 0;
    for (int i = threadIdx.x; i < 65536; i += 256) {
        unsigned e = (xw[i] >> 7) & 0xFF;
        if (e >= 0xF0) localBig = 1;
    }
    for (int i = threadIdx.x; i < 8192; i += 256) {
        if (ew[2 * i + 1] != 0) localHigh = 1;
    }
    if (localBig) atomicOr(&sawBigExp, 1);
    if (localHigh) atomicOr(&sawHigh, 1);
    __syncthreads();
    if (threadIdx.x == 0) { flags[0] = sawBigExp; flags[1] = sawHigh ? 0 : 1; }
}

// ---------------- convert all float params to f32 arena ----------------
__global__ void cvt_params_kernel(Ptr17 ptrs, const int* __restrict__ flags,
                                  float* __restrict__ dst) {
    int i = blockIdx.x * 256 + threadIdx.x;
    if (i >= PARAM_TOTAL) return;
    const int ksz[17] = {81,3,81,3,31104,128,31104,128,49152,384,49152,384,384,16384,128,640,5};
    int seg = 0, off = i;
    while (off >= ksz[seg]) { off -= ksz[seg]; ++seg; }
    float v;
    if (flags[0]) v = ((const float*)ptrs.p[seg])[off];
    else          v = __bfloat162float(((const bf16*)ptrs.p[seg])[off]);
    dst[i] = v;
}

// ---------------- build bf16 transposed weight arenas ----------------
__global__ void cvt2_kernel(const float* __restrict__ P,
                            unsigned short* __restrict__ wtl,
                            unsigned short* __restrict__ wts,
                            unsigned short* __restrict__ wtm) {
    int i = blockIdx.x * 256 + threadIdx.x;
    if (i < WTL_N) {
        int f = i >> 8, k = i & 255;
        float v = 0.f;
        if (k < 243) v = (f < 128) ? P[OFF_LIN_W + k * 128 + f]
                                   : P[OFF_LIN_SW + k * 128 + (f - 128)];
        wtl[i] = f2b(v);
    } else if (i < WTL_N + WTS_N) {
        int j = i - WTL_N; int l = j >> 15; int r = j & 32767; int f = r >> 8; int k = r & 255;
        float v = (k < 128) ? P[OFF_SAGE_LW + l * 16384 + k * 128 + f]
                            : P[OFF_SAGE_RW + l * 16384 + (k - 128) * 128 + f];
        wts[j] = f2b(v);
    } else if (i < WTL_N + WTS_N + WTM_N) {
        int j = i - WTL_N - WTS_N; int f = j >> 7, k = j & 127;
        wtm[j] = f2b(P[OFF_MLP_W1 + k * 128 + f]);
    }
}

// ---------------- Stage 1: conv+relu (VALU) -> 243->256 linear (MFMA) ----------------
__global__ __launch_bounds__(256) void conv_lin_kernel(
    const void* __restrict__ x, const float* __restrict__ P,
    const unsigned short* __restrict__ wtl, const int* __restrict__ flags,
    unsigned short* __restrict__ xnb, float* __restrict__ selfh)
{
    __shared__ float xs[CONV_NB][368];            // stride 368: 16j mod 32 + 11*oi distinct
    __shared__ unsigned short ysb[16][2][256];    // relu(conv) bf16, K padded to 256, cols 14-15 zero
    __shared__ float wconv[2][81];
    __shared__ float bconv[2][3];
    int tid = threadIdx.x;
    int n0 = blockIdx.x * CONV_NB;

    if (tid < 81) { wconv[0][tid] = P[OFF_CONV_W + tid]; wconv[1][tid] = P[OFF_CONV_SW + tid]; }
    else if (tid < 84) { int o = tid - 81; bconv[0][o] = P[OFF_CONV_B + o]; bconv[1][o] = P[OFF_CONV_SB + o]; }

    {   // zero ysb (covers K padding 243..255 and pad cols 14,15)
        unsigned int* z = (unsigned int*)ysb;
        #pragma unroll
        for (int i = tid; i < 16 * 2 * 128; i += 256) z[i] = 0;
    }
    if (flags[0]) {
        const float* xf = (const float*)x;
        for (int i = tid; i < CONV_NB * 363; i += 256) {
            int j = i / 363, q = i - j * 363;
            int node = n0 + j;
            xs[j][q] = (node < N_NODES) ? xf[(size_t)node * 363 + q] : 0.f;
        }
    } else {
        const unsigned short* xb = (const unsigned short*)x;
        for (int i = tid; i < CONV_NB * 363; i += 256) {
            int j = i / 363, q = i - j * 363;
            int node = n0 + j;
            xs[j][q] = (node < N_NODES) ? blo(xb[(size_t)node * 363 + q]) : 0.f;
        }
    }
    __syncthreads();

    // conv: one unit per thread: (node j, path p, output row oi) -> 27 outputs
    if (tid < CONV_NB * 18) {
        int j = tid / 18, rem = tid - j * 18;
        int p = rem / 9, oi = rem - p * 9;
        float acc[27];
        #pragma unroll
        for (int o = 0; o < 3; o++) {
            float b = bconv[p][o];
            #pragma unroll
            for (int oj = 0; oj < 9; oj++) acc[o * 9 + oj] = b;
        }
        #pragma unroll
        for (int c = 0; c < 3; c++) {
            #pragma unroll
            for (int ki = 0; ki < 3; ki++) {
                float xr[11];
                const float* row = &xs[j][c * 121 + (oi + ki) * 11];
                #pragma unroll
                for (int t = 0; t < 11; t++) xr[t] = row[t];
                #pragma unroll
                for (int o = 0; o < 3; o++) {
                    int wb = o * 27 + c * 9 + ki * 3;
                    float w0 = wconv[p][wb], w1 = wconv[p][wb + 1], w2 = wconv[p][wb + 2];
                    #pragma unroll
                    for (int oj = 0; oj < 9; oj++)
                        acc[o * 9 + oj] += xr[oj] * w0 + xr[oj + 1] * w1 + xr[oj + 2] * w2;
                }
            }
        }
        #pragma unroll
        for (int o = 0; o < 3; o++)
            #pragma unroll
            for (int oj = 0; oj < 9; oj++)
                ysb[j][p][o * 81 + oi * 9 + oj] = f2b(fmaxf(acc[o * 9 + oj], 0.f));
    }
    __syncthreads();

    // MFMA: [16 nodes][256 k] x [256 k][256 f]; waves 0-1 -> path0 (f 0..127), 2-3 -> path1
    int wave = tid >> 6, lane = tid & 63, quad = lane >> 4, col = lane & 15;
    int p = wave >> 1;
    v4f acc[4];
    #pragma unroll
    for (int t = 0; t < 4; t++) { acc[t][0] = 0.f; acc[t][1] = 0.f; acc[t][2] = 0.f; acc[t][3] = 0.f; }
    for (int s = 0; s < 8; s++) {
        int kq = s * 32 + quad * 8;
        v8s a = *(const v8s*)&ysb[col][p][kq];
        #pragma unroll
        for (int t = 0; t < 4; t++) {
            int f = (wave * 4 + t) * 16 + col;
            v8s b = *(const v8s*)&wtl[(size_t)f * 256 + kq];
            acc[t] = __builtin_amdgcn_mfma_f32_16x16x32_bf16(a, b, acc[t], 0, 0, 0);
        }
    }
    #pragma unroll
    for (int t = 0; t < 4; t++) {
        int f = (wave * 4 + t) * 16 + col;
        #pragma unroll
        for (int r = 0; r < 4; r++) {
            int jj = quad * 4 + r;
            int node = n0 + jj;
            if (jj < CONV_NB && node < N_NODES) {
                float v = acc[t][r];
                if (p == 0) xnb[(size_t)node * 128 + f] = f2b(v + P[OFF_LIN_B + f]);
                else        selfh[(size_t)node * 128 + (f - 128)] = v + P[OFF_LIN_SB + (f - 128)];
            }
        }
    }
}

// ---------------- edge loads ----------------
__device__ __forceinline__ int ld_edge(const int* __restrict__ ew, size_t elem, int isi64) {
    size_t idx = isi64 ? (elem * 2) : elem;
    return ew[idx];
}

// ---------------- CSR build ----------------
__global__ void degree_kernel(const int* __restrict__ ew, const int* __restrict__ flags,
                              int* __restrict__ deg) {
    int e = blockIdx.x * blockDim.x + threadIdx.x;
    if (e < N_EDGES) {
        int d = ld_edge(ew, (size_t)N_EDGES + e, flags[1]);
        if ((unsigned)d < N_NODES) atomicAdd(&deg[d], 1);
    }
}

__global__ __launch_bounds__(1024) void scanA(const int* __restrict__ deg, int* __restrict__ rowptr,
                                              float* __restrict__ cntf, int* __restrict__ bsum) {
    __shared__ int s[1024];
    int tid = threadIdx.x;
    int i = blockIdx.x * 1024 + tid;
    int v = (i < N_NODES) ? deg[i] : 0;
    s[tid] = v;
    __syncthreads();
    for (int off = 1; off < 1024; off <<= 1) {
        int t = (tid >= off) ? s[tid - off] : 0;
        __syncthreads();
        s[tid] += t;
        __syncthreads();
    }
    if (i < N_NODES) {
        rowptr[i] = s[tid] - v;
        cntf[i] = (float)(v < 1 ? 1 : v);
    }
    if (tid == 1023) bsum[blockIdx.x] = s[1023];
}

__global__ void scanB(const int* __restrict__ bsum, int* __restrict__ boff, int nb, int* __restrict__ rowptr_end) {
    if (threadIdx.x == 0 && blockIdx.x == 0) {
        int run = 0;
        for (int i = 0; i < nb; i++) { boff[i] = run; run += bsum[i]; }
        *rowptr_end = run;
    }
}

__global__ __launch_bounds__(1024) void scanC(int* __restrict__ rowptr, const int* __restrict__ boff,
                                              int* __restrict__ cursor) {
    int i = blockIdx.x * 1024 + threadIdx.x;
    if (i < N_NODES) {
        int v = rowptr[i] + boff[blockIdx.x];
        rowptr[i] = v;
        cursor[i] = v;
    }
}

__global__ void fill_kernel(const int* __restrict__ ew, const int* __restrict__ flags,
                            int* __restrict__ cursor, int* __restrict__ csr) {
    int e = blockIdx.x * blockDim.x + threadIdx.x;
    if (e < N_EDGES) {
        int isi64 = flags[1];
        int s = ld_edge(ew, (size_t)e, isi64);
        int d = ld_edge(ew, (size_t)N_EDGES + e, isi64);
        if ((unsigned)d < N_NODES) {
            int p = atomicAdd(&cursor[d], 1);
            if ((unsigned)p < N_EDGES)
                csr[p] = ((unsigned)s < N_NODES) ? (s | ((s == d) ? (int)0x80000000 : 0)) : -1;
        }
    }
}

// ---------------- agg0 + relu + LN0 ----------------
// wave per node; 4 edges in flight: lane group g=lane>>4 -> edge, c=lane&15 -> 16B feature chunk
__global__ __launch_bounds__(256) void agg0ln_kernel(const unsigned short* __restrict__ xnb,
        const float* __restrict__ selfh, const int* __restrict__ rowptr, const int* __restrict__ csr,
        const float* __restrict__ lng, const float* __restrict__ lnb,
        unsigned short* __restrict__ zb) {
    int wave = threadIdx.x >> 6, lane = threadIdx.x & 63;
    int g = lane >> 4, c = lane & 15;
    int n = blockIdx.x * 4 + wave;
    int beg = rowptr[n], end = rowptr[n + 1];
    float a[8];
    #pragma unroll
    for (int i = 0; i < 8; i++) a[i] = 0.f;
    const uint4* x4 = (const uint4*)xnb;
    for (int e = beg; e < end; e += 4) {
        int ee = e + g;
        int sv = (ee < end) ? csr[ee] : -1;
        bool valid = ((unsigned)sv < N_NODES);       // excludes self loops (bit31) and invalid
        int svc = valid ? sv : 0;
        uint4 v = x4[(size_t)svc * 16 + c];
        if (valid) {
            a[0] += blo(v.x); a[1] += bhi(v.x);
            a[2] += blo(v.y); a[3] += bhi(v.y);
            a[4] += blo(v.z); a[5] += bhi(v.z);
            a[6] += blo(v.w); a[7] += bhi(v.w);
        }
    }
    #pragma unroll
    for (int i = 0; i < 8; i++) {
        a[i] += __shfl_xor(a[i], 16, 64);
        a[i] += __shfl_xor(a[i], 32, 64);
    }
    if (g == 0) {
        const float4* s4 = (const float4*)(selfh + (size_t)n * 128 + c * 8);
        float4 s0 = s4[0], s1 = s4[1];
        float v[8];
        v[0] = s0.x + a[0]; v[1] = s0.y + a[1]; v[2] = s0.z + a[2]; v[3] = s0.w + a[3];
        v[4] = s1.x + a[4]; v[5] = s1.y + a[5]; v[6] = s1.z + a[6]; v[7] = s1.w + a[7];
        float s = 0.f, sq = 0.f;
        #pragma unroll
        for (int i = 0; i < 8; i++) {
            v[i] = fmaxf(v[i], 0.f);
            s += v[i]; sq += v[i] * v[i];
        }
        #pragma unroll
        for (int m = 8; m >= 1; m >>= 1) {
            s  += __shfl_xor(s, m, 64);
            sq += __shfl_xor(sq, m, 64);
        }
        float mu = s * (1.f / 128.f);
        float var = sq * (1.f / 128.f) - mu * mu;
        float is = rsqrtf(var + LN_EPS);
        const float4* g4 = (const float4*)(lng + c * 8);
        const float4* b4 = (const float4*)(lnb + c * 8);
        float4 g0 = g4[0], g1 = g4[1], b0 = b4[0], b1 = b4[1];
        float z[8];
        z[0] = (v[0] - mu) * is * g0.x + b0.x; z[1] = (v[1] - mu) * is * g0.y + b0.y;
        z[2] = (v[2] - mu) * is * g0.z + b0.z; z[3] = (v[3] - mu) * is * g0.w + b0.w;
        z[4] = (v[4] - mu) * is * g1.x + b1.x; z[5] = (v[5] - mu) * is * g1.y + b1.y;
        z[6] = (v[6] - mu) * is * g1.z + b1.z; z[7] = (v[7] - mu) * is * g1.w + b1.w;
        uint4 o;
        o.x = pack2(z[0], z[1]); o.y = pack2(z[2], z[3]);
        o.z = pack2(z[4], z[5]); o.w = pack2(z[6], z[7]);
        ((uint4*)zb)[(size_t)n * 16 + c] = o;
    }
}

// ---------------- SAGE mean aggregation (4 edges in flight) ----------------
__global__ __launch_bounds__(256) void aggm_kernel(const unsigned short* __restrict__ zb,
        const int* __restrict__ rowptr, const int* __restrict__ csr,
        const float* __restrict__ cntf, unsigned short* __restrict__ aggb) {
    int wave = threadIdx.x >> 6, lane = threadIdx.x & 63;
    int g = lane >> 4, c = lane & 15;
    int n = blockIdx.x * 4 + wave;
    int beg = rowptr[n], end = rowptr[n + 1];
    float a[8];
    #pragma unroll
    for (int i = 0; i < 8; i++) a[i] = 0.f;
    const uint4* z4 = (const uint4*)zb;
    for (int e = beg; e < end; e += 4) {
        int ee = e + g;
        int sv = (ee < end) ? (csr[ee] & 0x7fffffff) : 0x7fffffff;  // SAGE keeps self loops
        bool valid = (sv < N_NODES);
        int svc = valid ? sv : 0;
        uint4 v = z4[(size_t)svc * 16 + c];
        if (valid) {
            a[0] += blo(v.x); a[1] += bhi(v.x);
            a[2] += blo(v.y); a[3] += bhi(v.y);
            a[4] += blo(v.z); a[5] += bhi(v.z);
            a[6] += blo(v.w); a[7] += bhi(v.w);
        }
    }
    #pragma unroll
    for (int i = 0; i < 8; i++) {
        a[i] += __shfl_xor(a[i], 16, 64);
        a[i] += __shfl_xor(a[i], 32, 64);
    }
    if (g == 0) {
        float inv = 1.f / cntf[n];
        uint4 o;
        o.x = pack2(a[0] * inv, a[1] * inv); o.y = pack2(a[2] * inv, a[3] * inv);
        o.z = pack2(a[4] * inv, a[5] * inv); o.w = pack2(a[6] * inv, a[7] * inv);
        ((uint4*)aggb)[(size_t)n * 16 + c] = o;
    }
}

// ---------------- SAGE update (MFMA, concat-K) + fused relu+LN (or final h) ----------------
__global__ __launch_bounds__(256) void sageln_kernel(const unsigned short* __restrict__ aggb,
        unsigned short* __restrict__ zb, const unsigned short* __restrict__ wts,
        const float* __restrict__ lb, const float* __restrict__ lng, const float* __restrict__ lnb,
        int last, float* __restrict__ hout) {
    __shared__ float hb[16][128];
    int tid = threadIdx.x;
    int n0 = blockIdx.x * 16;
    int wave = tid >> 6, lane = tid & 63, quad = lane >> 4, col = lane & 15;
    int nodeA = n0 + col;

    v4f acc[2];
    #pragma unroll
    for (int t = 0; t < 2; t++) { acc[t][0] = 0.f; acc[t][1] = 0.f; acc[t][2] = 0.f; acc[t][3] = 0.f; }
    #pragma unroll
    for (int s = 0; s < 8; s++) {
        int kq = s * 32 + quad * 8;
        const unsigned short* abase = (s < 4) ? (aggb + (size_t)nodeA * 128 + kq)
                                              : (zb + (size_t)nodeA * 128 + (kq - 128));
        v8s a = *(const v8s*)abase;
        #pragma unroll
        for (int t = 0; t < 2; t++) {
            int f = (wave * 2 + t) * 16 + col;
            v8s b = *(const v8s*)&wts[(size_t)f * 256 + kq];
            acc[t] = __builtin_amdgcn_mfma_f32_16x16x32_bf16(a, b, acc[t], 0, 0, 0);
        }
    }
    #pragma unroll
    for (int t = 0; t < 2; t++) {
        int f = (wave * 2 + t) * 16 + col;
        float bias = lb[f];
        #pragma unroll
        for (int r = 0; r < 4; r++)
            hb[quad * 4 + r][f] = acc[t][r] + bias;
    }
    __syncthreads();

    #pragma unroll
    for (int jj = 0; jj < 4; jj++) {
        int j = wave * 4 + jj;
        int node = n0 + j;
        float v0 = hb[j][2 * lane], v1 = hb[j][2 * lane + 1];
        if (last) {
            float2 w; w.x = v0; w.y = v1;
            ((float2*)hout)[(size_t)node * 64 + lane] = w;
        } else {
            float r0 = fmaxf(v0, 0.f), r1 = fmaxf(v1, 0.f);
            float s = r0 + r1, sq = r0 * r0 + r1 * r1;
            #pragma unroll
            for (int m = 32; m >= 1; m >>= 1) {
                s  += __shfl_xor(s, m, 64);
                sq += __shfl_xor(sq, m, 64);
            }
            float mu = s * (1.f / 128.f);
            float var = sq * (1.f / 128.f) - mu * mu;
            float inv = rsqrtf(var + LN_EPS);
            float z0 = (r0 - mu) * inv * lng[2 * lane]     + lnb[2 * lane];
            float z1 = (r1 - mu) * inv * lng[2 * lane + 1] + lnb[2 * lane + 1];
            ((unsigned int*)zb)[(size_t)node * 64 + lane] = pack2(z0, z1);
        }
    }
}

// ---------------- MLP head (MFMA w1) + log_softmax + fused emb cast ----------------
__global__ __launch_bounds__(256) void mlp_kernel(const float* __restrict__ h,
        const unsigned short* __restrict__ wtm, const float* __restrict__ P,
        const int* __restrict__ flags, void* __restrict__ out) {
    __shared__ unsigned short rb[16][128];
    __shared__ float mb[16][128];
    __shared__ float lg[16][5];
    int tid = threadIdx.x;
    int n0 = blockIdx.x * 16;
    int isf = flags[0];

    const float2* h2 = (const float2*)h;
    for (int i = tid; i < 16 * 64; i += 256) {
        int j = i >> 6, q = i & 63;
        float2 v = h2[(size_t)(n0 + j) * 64 + q];
        size_t oi = (size_t)(n0 + j) * 128 + 2 * q;
        if (isf) { ((float*)out)[oi] = v.x; ((float*)out)[oi + 1] = v.y; }
        else ((unsigned int*)out)[oi >> 1] = pack2(v.x, v.y);
        rb[j][2 * q]     = f2b(fmaxf(v.x, 0.f));
        rb[j][2 * q + 1] = f2b(fmaxf(v.y, 0.f));
    }
    __syncthreads();

    int wave = tid >> 6, lane = tid & 63, quad = lane >> 4, col = lane & 15;
    v4f acc[2];
    #pragma unroll
    for (int t = 0; t < 2; t++) { acc[t][0] = 0.f; acc[t][1] = 0.f; acc[t][2] = 0.f; acc[t][3] = 0.f; }
    #pragma unroll
    for (int s = 0; s < 4; s++) {
        int kq = s * 32 + quad * 8;
        v8s a = *(const v8s*)&rb[col][kq];
        #pragma unroll
        for (int t = 0; t < 2; t++) {
            int f = (wave * 2 + t) * 16 + col;
            v8s b = *(const v8s*)&wtm[(size_t)f * 128 + kq];
            acc[t] = __builtin_amdgcn_mfma_f32_16x16x32_bf16(a, b, acc[t], 0, 0, 0);
        }
    }
    #pragma unroll
    for (int t = 0; t < 2; t++) {
        int f = (wave * 2 + t) * 16 + col;
        float bias = P[OFF_MLP_B1 + f];
        #pragma unroll
        for (int r = 0; r < 4; r++)
            mb[quad * 4 + r][f] = acc[t][r] + bias;
    }
    __syncthreads();

    if (tid < 80) {
        int j = tid / 5, o = tid - (tid / 5) * 5;
        float a = P[OFF_MLP_B2 + o];
        for (int k = 0; k < 128; k++) a += mb[j][k] * P[OFF_MLP_W2 + k * 5 + o];
        lg[j][o] = a;
    }
    __syncthreads();
    if (tid < 16) {
        int j = tid;
        float mx = lg[j][0];
        #pragma unroll
        for (int o = 1; o < 5; o++) mx = fmaxf(mx, lg[j][o]);
        float se = 0.f;
        #pragma unroll
        for (int o = 0; o < 5; o++) se += expf(lg[j][o] - mx);
        float lse = mx + logf(se);
        size_t base = (size_t)N_NODES * 128 + (size_t)(n0 + j) * 5;
        #pragma unroll
        for (int o = 0; o < 5; o++) {
            float v = lg[j][o] - lse;
            if (isf) ((float*)out)[base + o] = v;
            else     ((bf16*)out)[base + o] = __float2bfloat16(v);
        }
    }
}

extern "C" void kernel_launch(void* const* d_in, const int* in_sizes, int n_in,
                              void* d_out, int out_size, void* d_ws, size_t ws_size,
                              hipStream_t stream) {
    const void* x  = d_in[0];
    const int*  ew = (const int*)d_in[1];

    Ptr17 ptrs;
    for (int i = 0; i < 17; i++) ptrs.p[i] = d_in[2 + i];

    char* w = (char*)d_ws;
    auto carve = [&](size_t bytes) { char* r = w; w += (bytes + 255) & ~(size_t)255; return r; };
    float*          bufS  = (float*)carve((size_t)N_NODES * 128 * 4);   // selfh, later final h
    unsigned short* xnb   = (unsigned short*)carve((size_t)N_NODES * 128 * 2);
    unsigned short* zb    = (unsigned short*)carve((size_t)N_NODES * 128 * 2);
    unsigned short* aggb  = (unsigned short*)carve((size_t)N_NODES * 128 * 2);
    float*          pf32  = (float*)carve((size_t)PARAM_TOTAL * 4);
    unsigned short* wtl   = (unsigned short*)carve((size_t)WTL_N * 2);
    unsigned short* wts   = (unsigned short*)carve((size_t)WTS_N * 2);
    unsigned short* wtm   = (unsigned short*)carve((size_t)WTM_N * 2);
    int*   deg    = (int*)carve((size_t)N_NODES * 4);
    int*   rowptr = (int*)carve((size_t)(N_NODES + 64) * 4);
    int*   cursor = (int*)carve((size_t)N_NODES * 4);
    float* cntf   = (float*)carve((size_t)N_NODES * 4);
    int*   bsum   = (int*)carve(512);
    int*   boff   = (int*)carve(512);
    int*   flags  = (int*)carve(256);
    int*   csr    = (int*)carve((size_t)N_EDGES * 4);

    const int SCAN_BLOCKS = (N_NODES + 1023) / 1024;
    const int CONV_BLOCKS = (N_NODES + CONV_NB - 1) / CONV_NB;

    detect_kernel<<<1, 256, 0, stream>>>((const unsigned short*)x, (const unsigned int*)ew, flags);
    cvt_params_kernel<<<(PARAM_TOTAL + 255) / 256, 256, 0, stream>>>(ptrs, flags, pf32);
    cvt2_kernel<<<(WTL_N + WTS_N + WTM_N + 255) / 256, 256, 0, stream>>>(pf32, wtl, wts, wtm);

    hipMemsetAsync(deg, 0, (size_t)N_NODES * 4, stream);

    conv_lin_kernel<<<CONV_BLOCKS, 256, 0, stream>>>(x, pf32, wtl, flags, xnb, bufS);

    degree_kernel<<<(N_EDGES + 255) / 256, 256, 0, stream>>>(ew, flags, deg);
    scanA<<<SCAN_BLOCKS, 1024, 0, stream>>>(deg, rowptr, cntf, bsum);
    scanB<<<1, 1, 0, stream>>>(bsum, boff, SCAN_BLOCKS, rowptr + N_NODES);
    scanC<<<SCAN_BLOCKS, 1024, 0, stream>>>(rowptr, boff, cursor);
    fill_kernel<<<(N_EDGES + 255) / 256, 256, 0, stream>>>(ew, flags, cursor, csr);

    agg0ln_kernel<<<N_NODES / 4, 256, 0, stream>>>(xnb, bufS, rowptr, csr,
        pf32 + OFF_LN_G, pf32 + OFF_LN_B, zb);

    for (int l = 0; l < 3; l++) {
        aggm_kernel<<<N_NODES / 4, 256, 0, stream>>>(zb, rowptr, csr, cntf, aggb);
        sageln_kernel<<<N_NODES / 16, 256, 0, stream>>>(aggb, zb, wts + (size_t)l * 32768,
            pf32 + OFF_SAGE_LB + l * 128,
            pf32 + OFF_LN_G + (l + 1) * 128, pf32 + OFF_LN_B + (l + 1) * 128,
            (l == 2) ? 1 : 0, bufS);
    }

    mlp_kernel<<<N_NODES / 16, 256, 0, stream>>>(bufS, wtm, pf32, flags, d_out);
}